// Round 8
// baseline (152.926 us; speedup 1.0000x reference)
//
#include <hip/hip_runtime.h>

// ISTA T=5, LAM=0.1, B=L=4096, K=128.
// R11: counted-vmcnt ring pipeline (T3/T4) — never drain the DMA queue.
//  u = corr(y - corr(y,h), rev(h)) == (interior) one 255-tap correlation
//    G[t] = [t in [-63,64]] h[64-t] - ac[|t-1|],  ac[tau]=sum_m h[m]h[m+tau].
//  512 stream blocks (16 rows x 2048 cols, 2/CU). LDS: 8-slot ring of
//  128-col fp32 segs, [16 rows][1024 dw] = 64 KB exactly. 16 phases; phase k:
//    s_waitcnt vmcnt(16)   // segs k+3,k+4 stay in flight; seg k+2 landed
//    s_barrier; sched_barrier(0)
//    issue seg k+5 (8 size-4 global_load_lds per wave, linear dst)
//    compute 2 tiles/wave (persistent sliding 9-window bf16 frags)
//  Live slots {k-1..k+2 read, k+3..k+5 write} = 7 consecutive -> distinct
//  mod 8: race-free. Each seg has ~3 phases of latency cover; queue never
//  empties (48 KB/CU in flight).
//  r-truncation affects cols [0,64) u [L-64,L): exact two-pass edge blocks
//  (same launch, disjoint columns) fix those strips.
//  ISTA closed form (constant u): x_5 = 5*soft(s*u, LAM).

typedef __bf16 bf16;
typedef __bf16 bf16x4 __attribute__((ext_vector_type(4)));
typedef __bf16 bf16x8 __attribute__((ext_vector_type(8)));
typedef float f32x4 __attribute__((ext_vector_type(4)));

#define LAM 0.1f
// ws layout in bf16 elems (16-B aligned fragments):
#define WS_AG 0        // AG frag:  lane*128 + dd*8, dd<9
#define WS_ZERO 80     // 16 B of zeros inside lane0's AG gap
#define WS_A1 8192     // A1e frag: lane*64  + dd*8, dd<5
#define WS_A2 12288    // A2e frag: lane*64  + dd*8, dd<5
// edge-path LDS partition:
#define PYE 360        // y strip pitch (352 needed)
#define PRE 216        // r strip pitch (208 needed)

// ---------------- prep: G + lane-layout A-fragment tables ----------------
__global__ __launch_bounds__(256) void ista_prep(const float* __restrict__ h,
                                                 bf16* __restrict__ ws) {
  __shared__ float hs[256];    // h zero-padded
  __shared__ float acp[256];   // autocorr partials
  __shared__ bf16 gp[384];     // G[t] at p=t+144, zero outside
  const int tid = threadIdx.x;
  hs[tid] = (tid < 128) ? h[tid] : 0.f;
  gp[tid] = (bf16)0.f;
  if (tid < 128) gp[256 + tid] = (bf16)0.f;
  __syncthreads();
  const int tau = tid & 127;
  {  // split ac over two halves x 4 accumulators (short dep chains)
    const int m0 = (tid >> 7) * 64;
    float p0 = 0.f, p1 = 0.f, p2 = 0.f, p3 = 0.f;
    for (int m = m0; m < m0 + 64; m += 4) {
      p0 += hs[m] * hs[m + tau];     p1 += hs[m + 1] * hs[m + 1 + tau];
      p2 += hs[m + 2] * hs[m + 2 + tau]; p3 += hs[m + 3] * hs[m + 3 + tau];
    }
    acp[tid] = (p0 + p1) + (p2 + p3);
  }
  __syncthreads();
  if (tid < 128) {
    float ac = acp[tid] + acp[tid + 128];
    float g1 = (tau <= 63) ? hs[63 - tau] : 0.f;
    gp[145 + tau] = (bf16)(g1 - ac);
    if (tau > 0) {
      float g2 = (tau <= 64) ? hs[63 + tau] : 0.f;
      gp[145 - tau] = (bf16)(g2 - ac);
    }
  }
  __syncthreads();
  // AG lane-layout: A[m=li][k=quad*8+j] = G[144 + quad*8 - li + (dd-4)*32 + j]
  for (int i = tid; i < 1024; i += 256) {
    const int l = i >> 4, dd = i & 15;
    if (dd < 9) {
      const int o = 144 + (l >> 4) * 8 - (l & 15) + (dd - 4) * 32;
      bf16x8 a;
#pragma unroll
      for (int j = 0; j < 8; ++j) a[j] = gp[o + j];
      *reinterpret_cast<bf16x8*>(ws + WS_AG + l * 128 + dd * 8) = a;
    }
  }
  if (tid < 8) ws[WS_ZERO + tid] = (bf16)0.f;   // zero block for DMA halo
  // edge Toeplitz tables: h1p[p]=h[p-64], h2p[p]=-h[191-p] (zero outside)
  for (int i = tid; i < 512; i += 256) {
    const int l = i >> 3, dd = i & 7;
    if (dd < 5) {
      const int o = 127 + (l >> 4) * 8 - (l & 15) + (dd - 2) * 32;
      bf16x8 a1, a2;
#pragma unroll
      for (int j = 0; j < 8; ++j) {
        int p = o + j;
        int i1 = p - 64;
        a1[j] = ((unsigned)i1 < 128u) ? (bf16)hs[i1] : (bf16)0.f;
        int i2 = 191 - p;
        a2[j] = ((unsigned)i2 < 128u) ? (bf16)(-hs[i2]) : (bf16)0.f;
      }
      *reinterpret_cast<bf16x8*>(ws + WS_A1 + l * 64 + dd * 8) = a1;
      *reinterpret_cast<bf16x8*>(ws + WS_A2 + l * 64 + dd * 8) = a2;
    }
  }
}

// fp32 LDS ring row -> bf16x8 fragment (8 consecutive dwords, ring-wrapped)
__device__ __forceinline__ bf16x8 ldfrag(const float* __restrict__ rowb,
                                         int col) {
  const int X = col & 1023;            // col is a multiple of 8 -> no wrap
  float4 v0 = *reinterpret_cast<const float4*>(rowb + X);
  float4 v1 = *reinterpret_cast<const float4*>(rowb + X + 4);
  bf16x8 b;
  b[0] = (bf16)v0.x; b[1] = (bf16)v0.y; b[2] = (bf16)v0.z; b[3] = (bf16)v0.w;
  b[4] = (bf16)v1.x; b[5] = (bf16)v1.y; b[6] = (bf16)v1.z; b[7] = (bf16)v1.w;
  return b;
}

// ---------------- fused: counted-vmcnt ring stream + edge two-pass --------
__global__ __launch_bounds__(256) void ista_fused(
    const float* __restrict__ y, const bf16* __restrict__ ws,
    const float* __restrict__ step, float* __restrict__ out) {
  __shared__ __align__(16) char smem[65536];   // 64 KB: 2 blocks/CU
  const int tid = threadIdx.x;
  const int lane = tid & 63;
  const int li = lane & 15;
  const int quad = tid >> 4 & 3;  // == (lane>>4)
  const int wave = tid >> 6;
  const int bid = blockIdx.x;
  const float s = step[0];

  if (bid < 512) {
    // -------- stream: 16 rows x 2048 cols, 16 phases of 128 cols ----------
    // rowgroup-major: both strips of a rowgroup share an XCD (bid%8 const).
    const int b0 = (bid & 255) * 16;
    const int cb = (bid >> 8) * 2048;

    bf16x8 AG[9];
#pragma unroll
    for (int dd = 0; dd < 9; ++dd)
      AG[dd] = *reinterpret_cast<const bf16x8*>(ws + WS_AG + lane * 128 + dd * 8);

    const float* zsrc = reinterpret_cast<const float*>(ws + WS_ZERO);
    const int r0 = wave * 4;
    // issue seg m (cols cb+128m .. +127) -> ring slot (128m)&1023.
    // 8 size-4 DMAs per wave (rows r0..r0+3 x 2 quarters), ALWAYS issued
    // (OOB segs source the zero block) so vmcnt accounting stays exact.
    auto issue_seg = [&](int m) {
      const int base = cb + 128 * m;
      const bool oob = (base < 0) | (base >= 4096) | (m > 17);
      const int slotB = ((128 * m) & 1023) << 2;
#pragma unroll
      for (int t = 0; t < 8; ++t) {
        const int r = r0 + (t >> 1);
        const int q = t & 1;
        const float* src =
            oob ? zsrc : (y + (size_t)(b0 + r) * 4096 + base + 64 * q + lane);
        char* dst = smem + r * 4096 + slotB + q * 256;
        __builtin_amdgcn_global_load_lds(
            (const __attribute__((address_space(1))) void*)src,
            (__attribute__((address_space(3))) void*)dst, 4, 0, 0);
      }
    };

    // prologue: issue segs -1..4 (48 DMAs/wave)
#pragma unroll
    for (int m = -1; m <= 4; ++m) issue_seg(m);

    const int qo = quad << 3;
    const float* rowb = reinterpret_cast<const float*>(smem) + li * 1024;
    float* orow = out + (size_t)(b0 + li) * 4096 + cb + (quad << 2);
    bf16x8 B[9];

#pragma unroll
    for (int k = 0; k < 16; ++k) {
      // invariant at this wait: outstanding = segs k+2,k+3,k+4 (24 issues);
      // vmcnt(16) retires seg k+2 -> everything phase k reads has landed.
      asm volatile("s_waitcnt vmcnt(16)" ::: "memory");
      __builtin_amdgcn_s_barrier();
      __builtin_amdgcn_sched_barrier(0);
      issue_seg(k + 5);                 // lands ~3 phases from now
      if (k == 0) {
#pragma unroll
        for (int dd = 0; dd < 9; ++dd)
          B[dd] = ldfrag(rowb, 16 * wave + (dd - 4) * 32 + qo);
      }
#pragma unroll
      for (int j = 0; j < 2; ++j) {    // tiles tc, stride 64 across phases
        const int tc = 128 * k + 64 * j + 16 * wave;
        bf16x8 n0 = ldfrag(rowb, tc + 160 + qo);   // next tile's 2 windows
        bf16x8 n1 = ldfrag(rowb, tc + 192 + qo);
        f32x4 acc0 = {0.f, 0.f, 0.f, 0.f};
        f32x4 acc1 = {0.f, 0.f, 0.f, 0.f};
        acc0 = __builtin_amdgcn_mfma_f32_16x16x32_bf16(AG[0], B[0], acc0, 0, 0, 0);
        acc1 = __builtin_amdgcn_mfma_f32_16x16x32_bf16(AG[1], B[1], acc1, 0, 0, 0);
        acc0 = __builtin_amdgcn_mfma_f32_16x16x32_bf16(AG[2], B[2], acc0, 0, 0, 0);
        acc1 = __builtin_amdgcn_mfma_f32_16x16x32_bf16(AG[3], B[3], acc1, 0, 0, 0);
        acc0 = __builtin_amdgcn_mfma_f32_16x16x32_bf16(AG[4], B[4], acc0, 0, 0, 0);
        acc1 = __builtin_amdgcn_mfma_f32_16x16x32_bf16(AG[5], B[5], acc1, 0, 0, 0);
        acc0 = __builtin_amdgcn_mfma_f32_16x16x32_bf16(AG[6], B[6], acc0, 0, 0, 0);
        acc1 = __builtin_amdgcn_mfma_f32_16x16x32_bf16(AG[7], B[7], acc1, 0, 0, 0);
        acc0 = __builtin_amdgcn_mfma_f32_16x16x32_bf16(AG[8], B[8], acc0, 0, 0, 0);
        const int tabs = cb + tc;
        if (tabs >= 64 && tabs < 4032) {  // edge strips owned by edge blocks
          float4 xv;
#pragma unroll
          for (int e = 0; e < 4; ++e) {
            float su = s * (acc0[e] + acc1[e]);
            float ax = fabsf(su) - LAM;
            ax = ax > 0.f ? ax : 0.f;
            (&xv.x)[e] = 5.f * copysignf(ax, su);
          }
          *reinterpret_cast<float4*>(orow + tc) = xv;
        }
        B[0] = B[2]; B[1] = B[3]; B[2] = B[4]; B[3] = B[5]; B[4] = B[6];
        B[5] = B[7]; B[6] = B[8]; B[7] = n0; B[8] = n1;
      }
    }
  } else {
    // ---------------- edge: exact two-pass on 64-col strips ----------------
    const int eid = bid - 512;
    const int chunk0 = (eid & 1) ? (4096 - 64) : 0;
    const int b0 = (eid >> 1) * 16;
    bf16* ys = reinterpret_cast<bf16*>(smem);      // 16 x PYE, [-128, 224)
    bf16* rs = ys + 16 * PYE;                      // 16 x PRE, -r at [-64, 144)
    const int wv = wave;

    bf16x8 A1[5], A2[5];
#pragma unroll
    for (int dd = 0; dd < 5; ++dd) {
      A1[dd] = *reinterpret_cast<const bf16x8*>(ws + WS_A1 + lane * 64 + dd * 8);
      A2[dd] = *reinterpret_cast<const bf16x8*>(ws + WS_A2 + lane * 64 + dd * 8);
    }

    {  // stage y: 352 elems = 88 float4 per row (guarded)
      const int rr = tid >> 4;
      const int t = tid & 15;
      const float* yrow = y + (size_t)(b0 + rr) * 4096;
      bf16* dst = ys + rr * PYE;
#pragma unroll
      for (int k = 0; k < 6; ++k) {
        int s4 = t + 16 * k;
        if (s4 < 88) {
          int l = chunk0 - 128 + s4 * 4;
          float4 v;
          if (l >= 0 && l <= 4096 - 4) {
            v = *reinterpret_cast<const float4*>(yrow + l);
          } else {
            v.x = ((unsigned)(l + 0) < 4096u) ? yrow[l + 0] : 0.f;
            v.y = ((unsigned)(l + 1) < 4096u) ? yrow[l + 1] : 0.f;
            v.z = ((unsigned)(l + 2) < 4096u) ? yrow[l + 2] : 0.f;
            v.w = ((unsigned)(l + 3) < 4096u) ? yrow[l + 3] : 0.f;
          }
          bf16x4 bv;
          bv[0] = (bf16)v.x; bv[1] = (bf16)v.y; bv[2] = (bf16)v.z; bv[3] = (bf16)v.w;
          *reinterpret_cast<bf16x4*>(dst + s4 * 4) = bv;
        }
      }
    }
    __syncthreads();

    // conv1: tiles i0 = -64+16t, t in [0,13); emit -r (truncated to [0,L))
    for (int t = wv; t < 13; t += 4) {
      const int i0 = -64 + 16 * t;
      f32x4 acc;
      {
        bf16x4 yv = *reinterpret_cast<const bf16x4*>(
            ys + li * PYE + (i0 + 128) + quad * 4);
        acc[0] = -(float)yv[0]; acc[1] = -(float)yv[1];
        acc[2] = -(float)yv[2]; acc[3] = -(float)yv[3];
      }
#pragma unroll
      for (int dd = 0; dd < 5; ++dd) {
        bf16x8 b = *reinterpret_cast<const bf16x8*>(
            ys + li * PYE + (i0 + (dd - 2) * 32 + 128) + quad * 8);
        acc = __builtin_amdgcn_mfma_f32_16x16x32_bf16(A1[dd], b, acc, 0, 0, 0);
      }
      bf16x4 rv;
#pragma unroll
      for (int e = 0; e < 4; ++e) {
        int g = chunk0 + i0 + quad * 4 + e;
        float v = ((unsigned)g < 4096u) ? acc[e] : 0.f;
        rv[e] = (bf16)v;
      }
      *reinterpret_cast<bf16x4*>(rs + li * PRE + (i0 + 64) + quad * 4) = rv;
    }
    __syncthreads();

    // conv2 + closed-form epilogue: 4 tiles, one per wave
    {
      const int i0 = 16 * wv;
      f32x4 acc = {0.f, 0.f, 0.f, 0.f};
#pragma unroll
      for (int dd = 0; dd < 5; ++dd) {
        bf16x8 b = *reinterpret_cast<const bf16x8*>(
            rs + li * PRE + (i0 + (dd - 2) * 32 + 64) + quad * 8);
        acc = __builtin_amdgcn_mfma_f32_16x16x32_bf16(A2[dd], b, acc, 0, 0, 0);
      }
      float4 xv;
#pragma unroll
      for (int e = 0; e < 4; ++e) {
        float su = s * acc[e];
        float ax = fabsf(su) - LAM;
        ax = ax > 0.f ? ax : 0.f;
        (&xv.x)[e] = 5.f * copysignf(ax, su);
      }
      *reinterpret_cast<float4*>(
          out + (size_t)(b0 + li) * 4096 + chunk0 + i0 + quad * 4) = xv;
    }
  }
}

extern "C" void kernel_launch(void* const* d_in, const int* in_sizes, int n_in,
                              void* d_out, int out_size, void* d_ws,
                              size_t ws_size, hipStream_t stream) {
  const float* y = (const float*)d_in[0];
  const float* h = (const float*)d_in[1];
  const float* s = (const float*)d_in[2];
  float* out = (float*)d_out;
  bf16* ws = (bf16*)d_ws;   // 32 KB used
  ista_prep<<<dim3(1), dim3(256), 0, stream>>>(h, ws);
  // 512 stream blocks (16 rows x 2048 cols, counted-vmcnt ring) + 512 edge
  // blocks (cols [0,64) and [4032,4096)) — disjoint outputs, one launch.
  ista_fused<<<dim3(512 + 512), dim3(256), 0, stream>>>(y, ws, s, out);
}

// Round 9
// 134.581 us; speedup vs baseline: 1.1363x; 1.1363x over previous
//
#include <hip/hip_runtime.h>

// ISTA T=5, LAM=0.1, B=L=4096, K=128.
// R12: counted-vmcnt ring pipeline, bank-conflict-corrected (R11 errata: its
//  ring pitch was 4096 B = 0 mod 128 -> 16-way ds_read conflicts, 25.5M).
//  u = corr(y - corr(y,h), rev(h)) == (interior) one 255-tap correlation
//    G[t] = [t in [-63,64]] h[64-t] - ac[|t-1|],  ac[tau]=sum_m h[m]h[m+tau].
//  512 stream blocks (16 rows x 2048 cols, 3/CU). LDS: 6-slot ring of 128-col
//  fp32 segs, row pitch 772 dw (3088 B = 16 mod 128 -> 2-way = free).
//  Phase k (16 phases): issue seg k+4 (8 size-4 global_load_lds/wave);
//  compute 2 tiles/wave (sliding 9-window bf16 frags, incremental ring
//  offsets); s_waitcnt vmcnt(8) [retires seg k+3 only; k+4 stays in flight
//  ACROSS the barrier]; s_barrier; sched_barrier(0).
//  Live slots: readers {k-1..k+2} + writers {k+3,k+4} = 6 consecutive ->
//  distinct mod 6: race-free. Queue never drains.
//  r-truncation affects cols [0,64) u [L-64,L): exact two-pass edge blocks
//  (same launch, disjoint columns) fix those strips.
//  ISTA closed form (constant u): x_5 = 5*soft(s*u, LAM).

typedef __bf16 bf16;
typedef __bf16 bf16x4 __attribute__((ext_vector_type(4)));
typedef __bf16 bf16x8 __attribute__((ext_vector_type(8)));
typedef float f32x4 __attribute__((ext_vector_type(4)));

#define LAM 0.1f
#define RPDW 772                 // ring row pitch, fp32 dwords (3088 B)
#define RCOLS 768                // 6 slots x 128 cols
#define LDSB (16 * RPDW * 4)     // 49408 B -> 3 blocks/CU
// ws layout in bf16 elems (16-B aligned fragments):
#define WS_AG 0        // AG frag:  lane*128 + dd*8, dd<9
#define WS_ZERO 80     // 16 B of zeros inside lane0's AG gap
#define WS_A1 8192     // A1e frag: lane*64  + dd*8, dd<5
#define WS_A2 12288    // A2e frag: lane*64  + dd*8, dd<5
// edge-path LDS partition:
#define PYE 360        // y strip pitch (352 needed)
#define PRE 216        // r strip pitch (208 needed)

// ---------------- prep: G + lane-layout A-fragment tables ----------------
__global__ __launch_bounds__(256) void ista_prep(const float* __restrict__ h,
                                                 bf16* __restrict__ ws) {
  __shared__ float hs[256];    // h zero-padded
  __shared__ float acp[256];   // autocorr partials
  __shared__ bf16 gp[384];     // G[t] at p=t+144, zero outside
  const int tid = threadIdx.x;
  hs[tid] = (tid < 128) ? h[tid] : 0.f;
  gp[tid] = (bf16)0.f;
  if (tid < 128) gp[256 + tid] = (bf16)0.f;
  __syncthreads();
  const int tau = tid & 127;
  {  // split ac over two halves x 4 accumulators (short dep chains)
    const int m0 = (tid >> 7) * 64;
    float p0 = 0.f, p1 = 0.f, p2 = 0.f, p3 = 0.f;
    for (int m = m0; m < m0 + 64; m += 4) {
      p0 += hs[m] * hs[m + tau];     p1 += hs[m + 1] * hs[m + 1 + tau];
      p2 += hs[m + 2] * hs[m + 2 + tau]; p3 += hs[m + 3] * hs[m + 3 + tau];
    }
    acp[tid] = (p0 + p1) + (p2 + p3);
  }
  __syncthreads();
  if (tid < 128) {
    float ac = acp[tid] + acp[tid + 128];
    float g1 = (tau <= 63) ? hs[63 - tau] : 0.f;
    gp[145 + tau] = (bf16)(g1 - ac);
    if (tau > 0) {
      float g2 = (tau <= 64) ? hs[63 + tau] : 0.f;
      gp[145 - tau] = (bf16)(g2 - ac);
    }
  }
  __syncthreads();
  // AG lane-layout: A[m=li][k=quad*8+j] = G[144 + quad*8 - li + (dd-4)*32 + j]
  for (int i = tid; i < 1024; i += 256) {
    const int l = i >> 4, dd = i & 15;
    if (dd < 9) {
      const int o = 144 + (l >> 4) * 8 - (l & 15) + (dd - 4) * 32;
      bf16x8 a;
#pragma unroll
      for (int j = 0; j < 8; ++j) a[j] = gp[o + j];
      *reinterpret_cast<bf16x8*>(ws + WS_AG + l * 128 + dd * 8) = a;
    }
  }
  if (tid < 8) ws[WS_ZERO + tid] = (bf16)0.f;   // zero block for DMA halo
  // edge Toeplitz tables: h1p[p]=h[p-64], h2p[p]=-h[191-p] (zero outside)
  for (int i = tid; i < 512; i += 256) {
    const int l = i >> 3, dd = i & 7;
    if (dd < 5) {
      const int o = 127 + (l >> 4) * 8 - (l & 15) + (dd - 2) * 32;
      bf16x8 a1, a2;
#pragma unroll
      for (int j = 0; j < 8; ++j) {
        int p = o + j;
        int i1 = p - 64;
        a1[j] = ((unsigned)i1 < 128u) ? (bf16)hs[i1] : (bf16)0.f;
        int i2 = 191 - p;
        a2[j] = ((unsigned)i2 < 128u) ? (bf16)(-hs[i2]) : (bf16)0.f;
      }
      *reinterpret_cast<bf16x8*>(ws + WS_A1 + l * 64 + dd * 8) = a1;
      *reinterpret_cast<bf16x8*>(ws + WS_A2 + l * 64 + dd * 8) = a2;
    }
  }
}

// fp32 LDS ring row -> bf16x8 fragment (precomputed ring dword offset X,
// X multiple of 8, no mid-read wrap by construction)
__device__ __forceinline__ bf16x8 ldfragX(const float* __restrict__ rowb,
                                          int X) {
  float4 v0 = *reinterpret_cast<const float4*>(rowb + X);
  float4 v1 = *reinterpret_cast<const float4*>(rowb + X + 4);
  bf16x8 b;
  b[0] = (bf16)v0.x; b[1] = (bf16)v0.y; b[2] = (bf16)v0.z; b[3] = (bf16)v0.w;
  b[4] = (bf16)v1.x; b[5] = (bf16)v1.y; b[6] = (bf16)v1.z; b[7] = (bf16)v1.w;
  return b;
}

// ---------------- fused: counted-vmcnt ring stream + edge two-pass --------
__global__ __launch_bounds__(256) void ista_fused(
    const float* __restrict__ y, const bf16* __restrict__ ws,
    const float* __restrict__ step, float* __restrict__ out) {
  __shared__ __align__(16) char smem[LDSB];
  const int tid = threadIdx.x;
  const int lane = tid & 63;
  const int li = lane & 15;
  const int quad = (tid >> 4) & 3;
  const int wave = tid >> 6;
  const int bid = blockIdx.x;
  const float s = step[0];

  if (bid < 512) {
    // -------- stream: 16 rows x 2048 cols, 16 phases of 128 cols ----------
    // rowgroup-major: both strips of a rowgroup share an XCD (bid%8 const).
    const int b0 = (bid & 255) * 16;
    const int cb = (bid >> 8) * 2048;

    bf16x8 AG[9];
#pragma unroll
    for (int dd = 0; dd < 9; ++dd)
      AG[dd] = *reinterpret_cast<const bf16x8*>(ws + WS_AG + lane * 128 + dd * 8);

    const float* zsrc = reinterpret_cast<const float*>(ws + WS_ZERO);
    const int r0 = wave * 4;
    // issue seg m (cols cb+128m..+127) -> ring slot (m+6)%6. 8 size-4 DMAs
    // per wave (4 rows x 2 half-rows). ALWAYS issued (OOB -> zero block) so
    // vmcnt accounting stays exact. Uniform LDS base; per-lane global src.
    auto issue_seg = [&](int m) {
      const int base = cb + 128 * m;
      const bool oob = ((unsigned)base >= 4096u);
      const int slotB = (((m + 6) % 6) * 128) << 2;
#pragma unroll
      for (int t = 0; t < 8; ++t) {
        const int r = r0 + (t >> 1);
        const int q = t & 1;
        const float* src =
            oob ? zsrc : (y + (size_t)(b0 + r) * 4096 + base + 64 * q + lane);
        char* dst = smem + r * (RPDW * 4) + slotB + q * 256;
        __builtin_amdgcn_global_load_lds(
            (const __attribute__((address_space(1))) void*)src,
            (__attribute__((address_space(3))) void*)dst, 4, 0, 0);
      }
    };

    // prologue: issue segs -1..3 (40 issues/wave); retire through seg 2.
#pragma unroll
    for (int m = -1; m <= 3; ++m) issue_seg(m);
    asm volatile("s_waitcnt vmcnt(8)" ::: "memory");
    __builtin_amdgcn_s_barrier();
    __builtin_amdgcn_sched_barrier(0);

    const int qo = quad << 3;
    const float* rowb = reinterpret_cast<const float*>(smem) + li * RPDW;
    float* orow = out + (size_t)(b0 + li) * 4096 + cb + (quad << 2);

    // initial 9 windows for tile tc0 = 16*wave (cols -128..207 -> segs -1..1)
    bf16x8 B[9];
#pragma unroll
    for (int dd = 0; dd < 9; ++dd) {
      int col = 16 * wave + (dd - 4) * 32 + qo;
      B[dd] = ldfragX(rowb, (col + RCOLS) % RCOLS);
    }
    // incremental ring offsets for the per-tile prefetch reads
    int o0 = 16 * wave + 160 + qo;          // < RCOLS, no wrap at init
    int o1 = o0 + 32;

    for (int k = 0; k < 16; ++k) {
      issue_seg(k + 4);                     // lands ~2 phases from now
#pragma unroll
      for (int j = 0; j < 2; ++j) {         // tiles tc = 128k + 64j + 16*wave
        bf16x8 n0 = ldfragX(rowb, o0);
        bf16x8 n1 = ldfragX(rowb, o1);
        f32x4 acc0 = {0.f, 0.f, 0.f, 0.f};
        f32x4 acc1 = {0.f, 0.f, 0.f, 0.f};
        acc0 = __builtin_amdgcn_mfma_f32_16x16x32_bf16(AG[0], B[0], acc0, 0, 0, 0);
        acc1 = __builtin_amdgcn_mfma_f32_16x16x32_bf16(AG[1], B[1], acc1, 0, 0, 0);
        acc0 = __builtin_amdgcn_mfma_f32_16x16x32_bf16(AG[2], B[2], acc0, 0, 0, 0);
        acc1 = __builtin_amdgcn_mfma_f32_16x16x32_bf16(AG[3], B[3], acc1, 0, 0, 0);
        acc0 = __builtin_amdgcn_mfma_f32_16x16x32_bf16(AG[4], B[4], acc0, 0, 0, 0);
        acc1 = __builtin_amdgcn_mfma_f32_16x16x32_bf16(AG[5], B[5], acc1, 0, 0, 0);
        acc0 = __builtin_amdgcn_mfma_f32_16x16x32_bf16(AG[6], B[6], acc0, 0, 0, 0);
        acc1 = __builtin_amdgcn_mfma_f32_16x16x32_bf16(AG[7], B[7], acc1, 0, 0, 0);
        acc0 = __builtin_amdgcn_mfma_f32_16x16x32_bf16(AG[8], B[8], acc0, 0, 0, 0);
        const int tc = 128 * k + 64 * j + 16 * wave;
        const int tabs = cb + tc;
        if (tabs >= 64 && tabs < 4032) {    // edge strips owned by edge blocks
          float4 xv;
#pragma unroll
          for (int e = 0; e < 4; ++e) {
            float su = s * (acc0[e] + acc1[e]);
            float ax = fabsf(su) - LAM;
            ax = ax > 0.f ? ax : 0.f;
            (&xv.x)[e] = 5.f * copysignf(ax, su);
          }
          *reinterpret_cast<float4*>(orow + tc) = xv;
        }
        B[0] = B[2]; B[1] = B[3]; B[2] = B[4]; B[3] = B[5]; B[4] = B[6];
        B[5] = B[7]; B[6] = B[8]; B[7] = n0; B[8] = n1;
        o0 += 64; if (o0 >= RCOLS) o0 -= RCOLS;
        o1 += 64; if (o1 >= RCOLS) o1 -= RCOLS;
      }
      // retire seg k+3 only; seg k+4 (8 issues) stays in flight ACROSS the
      // barrier. Stores in flight only tighten the wait (safe).
      asm volatile("s_waitcnt vmcnt(8)" ::: "memory");
      __builtin_amdgcn_s_barrier();
      __builtin_amdgcn_sched_barrier(0);
    }
  } else {
    // ---------------- edge: exact two-pass on 64-col strips ----------------
    const int eid = bid - 512;
    const int chunk0 = (eid & 1) ? (4096 - 64) : 0;
    const int b0 = (eid >> 1) * 16;
    bf16* ys = reinterpret_cast<bf16*>(smem);      // 16 x PYE, [-128, 224)
    bf16* rs = ys + 16 * PYE;                      // 16 x PRE, -r at [-64, 144)
    const int wv = wave;

    bf16x8 A1[5], A2[5];
#pragma unroll
    for (int dd = 0; dd < 5; ++dd) {
      A1[dd] = *reinterpret_cast<const bf16x8*>(ws + WS_A1 + lane * 64 + dd * 8);
      A2[dd] = *reinterpret_cast<const bf16x8*>(ws + WS_A2 + lane * 64 + dd * 8);
    }

    {  // stage y: 352 elems = 88 float4 per row (guarded)
      const int rr = tid >> 4;
      const int t = tid & 15;
      const float* yrow = y + (size_t)(b0 + rr) * 4096;
      bf16* dst = ys + rr * PYE;
#pragma unroll
      for (int k = 0; k < 6; ++k) {
        int s4 = t + 16 * k;
        if (s4 < 88) {
          int l = chunk0 - 128 + s4 * 4;
          float4 v;
          if (l >= 0 && l <= 4096 - 4) {
            v = *reinterpret_cast<const float4*>(yrow + l);
          } else {
            v.x = ((unsigned)(l + 0) < 4096u) ? yrow[l + 0] : 0.f;
            v.y = ((unsigned)(l + 1) < 4096u) ? yrow[l + 1] : 0.f;
            v.z = ((unsigned)(l + 2) < 4096u) ? yrow[l + 2] : 0.f;
            v.w = ((unsigned)(l + 3) < 4096u) ? yrow[l + 3] : 0.f;
          }
          bf16x4 bv;
          bv[0] = (bf16)v.x; bv[1] = (bf16)v.y; bv[2] = (bf16)v.z; bv[3] = (bf16)v.w;
          *reinterpret_cast<bf16x4*>(dst + s4 * 4) = bv;
        }
      }
    }
    __syncthreads();

    // conv1: tiles i0 = -64+16t, t in [0,13); emit -r (truncated to [0,L))
    for (int t = wv; t < 13; t += 4) {
      const int i0 = -64 + 16 * t;
      f32x4 acc;
      {
        bf16x4 yv = *reinterpret_cast<const bf16x4*>(
            ys + li * PYE + (i0 + 128) + quad * 4);
        acc[0] = -(float)yv[0]; acc[1] = -(float)yv[1];
        acc[2] = -(float)yv[2]; acc[3] = -(float)yv[3];
      }
#pragma unroll
      for (int dd = 0; dd < 5; ++dd) {
        bf16x8 b = *reinterpret_cast<const bf16x8*>(
            ys + li * PYE + (i0 + (dd - 2) * 32 + 128) + quad * 8);
        acc = __builtin_amdgcn_mfma_f32_16x16x32_bf16(A1[dd], b, acc, 0, 0, 0);
      }
      bf16x4 rv;
#pragma unroll
      for (int e = 0; e < 4; ++e) {
        int g = chunk0 + i0 + quad * 4 + e;
        float v = ((unsigned)g < 4096u) ? acc[e] : 0.f;
        rv[e] = (bf16)v;
      }
      *reinterpret_cast<bf16x4*>(rs + li * PRE + (i0 + 64) + quad * 4) = rv;
    }
    __syncthreads();

    // conv2 + closed-form epilogue: 4 tiles, one per wave
    {
      const int i0 = 16 * wv;
      f32x4 acc = {0.f, 0.f, 0.f, 0.f};
#pragma unroll
      for (int dd = 0; dd < 5; ++dd) {
        bf16x8 b = *reinterpret_cast<const bf16x8*>(
            rs + li * PRE + (i0 + (dd - 2) * 32 + 64) + quad * 8);
        acc = __builtin_amdgcn_mfma_f32_16x16x32_bf16(A2[dd], b, acc, 0, 0, 0);
      }
      float4 xv;
#pragma unroll
      for (int e = 0; e < 4; ++e) {
        float su = s * acc[e];
        float ax = fabsf(su) - LAM;
        ax = ax > 0.f ? ax : 0.f;
        (&xv.x)[e] = 5.f * copysignf(ax, su);
      }
      *reinterpret_cast<float4*>(
          out + (size_t)(b0 + li) * 4096 + chunk0 + i0 + quad * 4) = xv;
    }
  }
}

extern "C" void kernel_launch(void* const* d_in, const int* in_sizes, int n_in,
                              void* d_out, int out_size, void* d_ws,
                              size_t ws_size, hipStream_t stream) {
  const float* y = (const float*)d_in[0];
  const float* h = (const float*)d_in[1];
  const float* s = (const float*)d_in[2];
  float* out = (float*)d_out;
  bf16* ws = (bf16*)d_ws;   // 32 KB used
  ista_prep<<<dim3(1), dim3(256), 0, stream>>>(h, ws);
  // 512 stream blocks (16 rows x 2048 cols, counted-vmcnt ring) + 512 edge
  // blocks (cols [0,64) and [4032,4096)) — disjoint outputs, one launch.
  ista_fused<<<dim3(512 + 512), dim3(256), 0, stream>>>(y, ws, s, out);
}